// Round 8
// baseline (378.056 us; speedup 1.0000x reference)
//
#include <hip/hip_runtime.h>
#include <hip/hip_bf16.h>
#include <math.h>

#define BB 4
#define TT 2048
#define DD 256
#define FF 1024
#define NL 4

typedef __bf16 bf16x8 __attribute__((ext_vector_type(8)));
typedef float f32x4 __attribute__((ext_vector_type(4)));

// fast exact-GELU: 0.5x(1+erf(x/sqrt2)), erf via A&S 7.1.26 (|err|<1.5e-7)
__device__ __forceinline__ float gelu_f(float v) {
  float x = fabsf(v) * 0.70710678118654752f;
  float t = 1.0f / fmaf(0.3275911f, x, 1.0f);
  float p = t * fmaf(t, fmaf(t, fmaf(t, fmaf(t, 1.061405429f, -1.453152027f),
                                     1.421413741f), -0.284496736f), 0.254829592f);
  float erfv = copysignf(1.0f - p * __expf(-x * x), v);
  return 0.5f * v * (1.0f + erfv);
}

// ---------------- prologue: weight f32->bf16 (blocks 0..3071) + PE+LN0 (rest) ----
__global__ __launch_bounds__(256) void prologue_kernel(
    const float4* __restrict__ wq, const float4* __restrict__ wo,
    const float4* __restrict__ w1, const float4* __restrict__ w2,
    ushort4* __restrict__ dst,
    const float* __restrict__ tokens, const float* __restrict__ g,
    const float* __restrict__ b, float* __restrict__ x,
    __hip_bfloat16* __restrict__ sb) {
  if (blockIdx.x < 3072) {
    int gi = blockIdx.x * 256 + threadIdx.x;
    const float4* src;
    int off;
    if (gi < 196608)      { src = wq; off = gi; }
    else if (gi < 262144) { src = wo; off = gi - 196608; }
    else if (gi < 524288) { src = w1; off = gi - 262144; }
    else                  { src = w2; off = gi - 524288; }
    float4 v = src[off];
    ushort4 o;
    o.x = __hip_bfloat16_raw(__float2bfloat16(v.x)).x;
    o.y = __hip_bfloat16_raw(__float2bfloat16(v.y)).x;
    o.z = __hip_bfloat16_raw(__float2bfloat16(v.z)).x;
    o.w = __hip_bfloat16_raw(__float2bfloat16(v.w)).x;
    dst[gi] = o;
    return;
  }
  int row = (blockIdx.x - 3072) * 4 + (threadIdx.x >> 6);
  int lane = threadIdx.x & 63;
  int t = row & (TT - 1);
  const float* xr = tokens + (size_t)row * DD;
  float v[4];
  float s = 0.f;
#pragma unroll
  for (int i = 0; i < 4; ++i) {
    int d = lane + 64 * i;
    int i2 = d & ~1;
    float freq = expf((float)i2 * -(9.210340371976184f / 256.f));
    float ang = (float)t * freq;
    float pe = (d & 1) ? cosf(ang) : sinf(ang);
    v[i] = xr[d] + pe;
    s += v[i];
  }
#pragma unroll
  for (int off = 32; off; off >>= 1) s += __shfl_xor(s, off, 64);
  float mu = s * (1.f / DD);
  float vs = 0.f;
#pragma unroll
  for (int i = 0; i < 4; ++i) { float dd = v[i] - mu; vs = fmaf(dd, dd, vs); }
#pragma unroll
  for (int off = 32; off; off >>= 1) vs += __shfl_xor(vs, off, 64);
  float rr = rsqrtf(vs * (1.f / DD) + 1e-5f);
#pragma unroll
  for (int i = 0; i < 4; ++i) {
    int d = lane + 64 * i;
    x[(size_t)row * DD + d] = v[i];
    sb[(size_t)row * DD + d] = __float2bfloat16((v[i] - mu) * rr * g[d] + b[d]);
  }
}

// ---------------- bf16 MFMA GEMM, chunked LDS, small tiles for high residency ----
// Block tile 32MW x 32NW, 4 waves 2x2 (wave tile 16MW x 16NW). LDS layout:
// [chunk c][row][32 bf16]. BK template; KTOT compile-time.
template <int MW, int NW, int BK, int KTOT, int ACT>
__global__ __launch_bounds__(256) void mgemm_kernel(
    const __hip_bfloat16* __restrict__ A, const __hip_bfloat16* __restrict__ B,
    const float* __restrict__ bias, __hip_bfloat16* __restrict__ Cout,
    int M, int N) {
  constexpr int BM = 32 * MW, BN = 32 * NW, ROWS = BM + BN;
  constexpr int NCH = BK / 32;
  constexpr int CHB = ROWS * 32;               // chunk stride in elems
  constexpr int RG = ROWS / 16;                // 16-row groups per chunk
  constexpr int NST = NCH * RG;                // stage instrs per kt-iter
  __shared__ __align__(16) __hip_bfloat16 sm[NCH * CHB];
  const int tid = threadIdx.x;
  const int wave = tid >> 6, lane = tid & 63;
  const int m0 = blockIdx.y * BM, n0 = blockIdx.x * BN;
  const int wm = (wave >> 1) * (16 * MW), wn = (wave & 1) * (16 * NW);
  const int quad = lane >> 4, lr = lane & 15;
  const int srow = lane >> 2, scol = (lane & 3) * 8;

  f32x4 acc[MW][NW] = {};

  for (int kt = 0; kt < KTOT; kt += BK) {
    __syncthreads();
#pragma unroll
    for (int i = 0; i < NST / 4; ++i) {
      int inst = i * 4 + wave;
      int c = inst / RG, grp = inst - c * RG;
      int r = grp * 16 + srow;
      const __hip_bfloat16* gp =
          (r < BM) ? (A + (size_t)(m0 + r) * KTOT + kt + c * 32 + scol)
                   : (B + (size_t)(n0 + (r - BM)) * KTOT + kt + c * 32 + scol);
      __builtin_amdgcn_global_load_lds(
          (const __attribute__((address_space(1))) unsigned int*)gp,
          (__attribute__((address_space(3))) unsigned int*)(sm + c * CHB + grp * 512),
          16, 0, 0);
    }
    __syncthreads();
#pragma unroll
    for (int c = 0; c < NCH; ++c) {
      bf16x8 af[MW], bfr[NW];
#pragma unroll
      for (int mi = 0; mi < MW; ++mi)
        af[mi] = *(const bf16x8*)(sm + c * CHB + (wm + mi * 16 + lr) * 32 + quad * 8);
#pragma unroll
      for (int ni = 0; ni < NW; ++ni)
        bfr[ni] = *(const bf16x8*)(sm + c * CHB + (BM + wn + ni * 16 + lr) * 32 + quad * 8);
#pragma unroll
      for (int mi = 0; mi < MW; ++mi)
#pragma unroll
        for (int ni = 0; ni < NW; ++ni)
          acc[mi][ni] = __builtin_amdgcn_mfma_f32_16x16x32_bf16(
              af[mi], bfr[ni], acc[mi][ni], 0, 0, 0);
    }
  }

#pragma unroll
  for (int mi = 0; mi < MW; ++mi) {
#pragma unroll
    for (int ni = 0; ni < NW; ++ni) {
      int col = n0 + wn + ni * 16 + lr;
      float bv = bias[col];
#pragma unroll
      for (int r = 0; r < 4; ++r) {
        int row = m0 + wm + mi * 16 + quad * 4 + r;
        float v = acc[mi][ni][r] + bv;
        if (ACT == 1) v = gelu_f(v);
        Cout[(size_t)row * N + col] = __float2bfloat16(v);
      }
    }
  }
}

// ---------------- bf16 GEMM, N=256 full-row, fused residual+LN (BK=64 chunks) ----
// BM=32, grid M/32=256. Wave w owns cols [64w,64w+64) x 32 rows.
template <int KTOT, int FIN>
__global__ __launch_bounds__(256) void mgemm_ln_kernel(
    const __hip_bfloat16* __restrict__ A, const __hip_bfloat16* __restrict__ B,
    const float* __restrict__ bias, const float* __restrict__ res,
    const float* __restrict__ g, const float* __restrict__ bb,
    float* __restrict__ xout, void* __restrict__ yout) {
  constexpr int BM = 32, ROWS = BM + 256;
  constexpr int BK = 64, NCH = BK / 32;
  constexpr int CHB = ROWS * 32;
  constexpr int RG = ROWS / 16;                // 18
  constexpr int NST = NCH * RG;                // 36
  __shared__ __align__(16) __hip_bfloat16 sm[NCH * CHB];
  __shared__ float red1[4][BM], red2[4][BM];
  const int tid = threadIdx.x;
  const int wave = tid >> 6, lane = tid & 63;
  const int quad = lane >> 4, lr = lane & 15;
  const int m0 = blockIdx.x * BM;
  const int srow = lane >> 2, scol = (lane & 3) * 8;

  f32x4 acc[2][4] = {};

  for (int kt = 0; kt < KTOT; kt += BK) {
    __syncthreads();
#pragma unroll
    for (int i = 0; i < NST / 4; ++i) {
      int inst = i * 4 + wave;
      int c = inst / RG, grp = inst - c * RG;
      int r = grp * 16 + srow;
      const __hip_bfloat16* gp =
          (r < BM) ? (A + (size_t)(m0 + r) * KTOT + kt + c * 32 + scol)
                   : (B + (size_t)(r - BM) * KTOT + kt + c * 32 + scol);
      __builtin_amdgcn_global_load_lds(
          (const __attribute__((address_space(1))) unsigned int*)gp,
          (__attribute__((address_space(3))) unsigned int*)(sm + c * CHB + grp * 512),
          16, 0, 0);
    }
    __syncthreads();
#pragma unroll
    for (int c = 0; c < NCH; ++c) {
      bf16x8 af[2], bfr[4];
#pragma unroll
      for (int mi = 0; mi < 2; ++mi)
        af[mi] = *(const bf16x8*)(sm + c * CHB + (mi * 16 + lr) * 32 + quad * 8);
#pragma unroll
      for (int ni = 0; ni < 4; ++ni)
        bfr[ni] = *(const bf16x8*)(sm + c * CHB + (BM + wave * 64 + ni * 16 + lr) * 32 + quad * 8);
#pragma unroll
      for (int mi = 0; mi < 2; ++mi)
#pragma unroll
        for (int ni = 0; ni < 4; ++ni)
          acc[mi][ni] = __builtin_amdgcn_mfma_f32_16x16x32_bf16(
              af[mi], bfr[ni], acc[mi][ni], 0, 0, 0);
    }
  }

  // epilogue: v = acc + bias + res; LN over full 256-col rows
  float v[2][4][4];
  float s1[2][4] = {}, s2[2][4] = {};
#pragma unroll
  for (int mi = 0; mi < 2; ++mi)
#pragma unroll
    for (int ni = 0; ni < 4; ++ni) {
      int col = wave * 64 + ni * 16 + lr;
      float bv = bias[col];
#pragma unroll
      for (int r = 0; r < 4; ++r) {
        int row = m0 + mi * 16 + quad * 4 + r;
        float val = acc[mi][ni][r] + bv + res[(size_t)row * DD + col];
        v[mi][ni][r] = val;
        s1[mi][r] += val;
        s2[mi][r] = fmaf(val, val, s2[mi][r]);
      }
    }
#pragma unroll
  for (int mi = 0; mi < 2; ++mi)
#pragma unroll
    for (int r = 0; r < 4; ++r) {
#pragma unroll
      for (int off = 8; off; off >>= 1) {
        s1[mi][r] += __shfl_xor(s1[mi][r], off, 64);
        s2[mi][r] += __shfl_xor(s2[mi][r], off, 64);
      }
    }
  if (lr == 0) {
#pragma unroll
    for (int mi = 0; mi < 2; ++mi)
#pragma unroll
      for (int r = 0; r < 4; ++r) {
        red1[wave][mi * 16 + quad * 4 + r] = s1[mi][r];
        red2[wave][mi * 16 + quad * 4 + r] = s2[mi][r];
      }
  }
  __syncthreads();
#pragma unroll
  for (int mi = 0; mi < 2; ++mi)
#pragma unroll
    for (int r = 0; r < 4; ++r) {
      int rl = mi * 16 + quad * 4 + r;
      float ssum = red1[0][rl] + red1[1][rl] + red1[2][rl] + red1[3][rl];
      float qsum = red2[0][rl] + red2[1][rl] + red2[2][rl] + red2[3][rl];
      float mu = ssum * (1.f / DD);
      float var = qsum * (1.f / DD) - mu * mu;
      float rr = rsqrtf(var + 1e-5f);
      int row = m0 + rl;
#pragma unroll
      for (int ni = 0; ni < 4; ++ni) {
        int col = wave * 64 + ni * 16 + lr;
        float y = (v[mi][ni][r] - mu) * rr * g[col] + bb[col];
        if (FIN) {
          ((float*)yout)[(size_t)row * DD + col] = y;
        } else {
          ((__hip_bfloat16*)yout)[(size_t)row * DD + col] = __float2bfloat16(y);
          xout[(size_t)row * DD + col] = v[mi][ni][r];
        }
      }
    }
}

// ---------------- sliding-window attention, MFMA (Vt XOR-swizzled) ----------------
__global__ __launch_bounds__(256) void attn_kernel(const __hip_bfloat16* __restrict__ qkv,
                                                   __hip_bfloat16* __restrict__ o) {
  __shared__ __align__(16) __hip_bfloat16 Ks[128][72];
  __shared__ __align__(16) __hip_bfloat16 Vt[64 * 136];
  __shared__ __align__(16) __hip_bfloat16 Ps[4][16][136];
  const int bh = blockIdx.y;
  const int b = bh >> 2, h = bh & 3;
  const int t0 = blockIdx.x * 64;
  const int sbase = t0 - 63;
  const int tid = threadIdx.x;

  const __hip_bfloat16* kb = qkv + (size_t)(b * TT) * 768 + 256 + h * 64;
  const __hip_bfloat16* vb = kb + 256;
  union U8 { uint4 u; __hip_bfloat16 hx[8]; };
#pragma unroll
  for (int it = 0; it < 4; ++it) {
    int f = tid + it * 256;
    int si = f >> 3;
    int c8 = f & 7;
    int s = sbase + si;
    U8 kr, vr;
    kr.u = make_uint4(0, 0, 0, 0); vr.u = make_uint4(0, 0, 0, 0);
    if (s >= 0 && s < TT) {
      kr.u = *(const uint4*)&kb[(size_t)s * 768 + 8 * c8];
      vr.u = *(const uint4*)&vb[(size_t)s * 768 + 8 * c8];
    }
    *(uint4*)&Ks[si][c8 * 8] = kr.u;
    int pc = (si >> 3) ^ c8;
#pragma unroll
    for (int j = 0; j < 8; ++j) Vt[(c8 * 8 + j) * 136 + pc * 8 + (si & 7)] = vr.hx[j];
  }
  __syncthreads();

  const int wave = tid >> 6, lane = tid & 63;
  const int quad = lane >> 4, lr = lane & 15;

  const __hip_bfloat16* qrow = qkv + (size_t)(b * TT + t0 + wave * 16 + lr) * 768 + h * 64;
  bf16x8 qa0 = *(const bf16x8*)(qrow + quad * 8);
  bf16x8 qa1 = *(const bf16x8*)(qrow + 32 + quad * 8);
  f32x4 sc[8];
#pragma unroll
  for (int c = 0; c < 8; ++c) {
    f32x4 a = {};
    bf16x8 kf0 = *(const bf16x8*)&Ks[c * 16 + lr][quad * 8];
    a = __builtin_amdgcn_mfma_f32_16x16x32_bf16(qa0, kf0, a, 0, 0, 0);
    bf16x8 kf1 = *(const bf16x8*)&Ks[c * 16 + lr][32 + quad * 8];
    a = __builtin_amdgcn_mfma_f32_16x16x32_bf16(qa1, kf1, a, 0, 0, 0);
    sc[c] = a;
  }

#pragma unroll
  for (int reg = 0; reg < 4; ++reg) {
    int dt = wave * 16 + quad * 4 + reg;
    float pv[8];
    float mx = -1e30f;
#pragma unroll
    for (int c = 0; c < 8; ++c) {
      int si = c * 16 + lr;
      float v = sc[c][reg] * 0.125f;
      bool ok = (si >= dt) && (si <= dt + 63) && (sbase + si >= 0);
      v = ok ? v : -1e30f;
      pv[c] = v;
      mx = fmaxf(mx, v);
    }
#pragma unroll
    for (int off = 8; off; off >>= 1) mx = fmaxf(mx, __shfl_xor(mx, off, 64));
    float l = 0.f;
#pragma unroll
    for (int c = 0; c < 8; ++c) { float e = __expf(pv[c] - mx); pv[c] = e; l += e; }
#pragma unroll
    for (int off = 8; off; off >>= 1) l += __shfl_xor(l, off, 64);
    float rinv = 1.f / l;
#pragma unroll
    for (int c = 0; c < 8; ++c)
      Ps[wave][quad * 4 + reg][c * 16 + lr] = __float2bfloat16(pv[c] * rinv);
  }

  __hip_bfloat16* obase = o + (size_t)(b * TT) * DD + h * 64;
#pragma unroll
  for (int ct = 0; ct < 4; ++ct) {
    f32x4 acc = {};
#pragma unroll
    for (int kk = 0; kk < 4; ++kk) {
      bf16x8 pa = *(const bf16x8*)&Ps[wave][lr][kk * 32 + quad * 8];
      int dd = ct * 16 + lr;
      bf16x8 vf = *(const bf16x8*)&Vt[dd * 136 + (((kk * 4 + quad) ^ (dd >> 3)) * 8)];
      acc = __builtin_amdgcn_mfma_f32_16x16x32_bf16(pa, vf, acc, 0, 0, 0);
    }
#pragma unroll
    for (int reg = 0; reg < 4; ++reg) {
      int t = t0 + wave * 16 + quad * 4 + reg;
      obase[(size_t)t * DD + ct * 16 + lr] = __float2bfloat16(acc[reg]);
    }
  }
}

extern "C" void kernel_launch(void* const* d_in, const int* in_sizes, int n_in,
                              void* d_out, int out_size, void* d_ws, size_t ws_size,
                              hipStream_t stream) {
  const float* tokens = (const float*)d_in[0];
  const float* Wqkv = (const float*)d_in[1];
  const float* bqkv = (const float*)d_in[2];
  const float* Wo   = (const float*)d_in[3];
  const float* bo   = (const float*)d_in[4];
  const float* W1   = (const float*)d_in[5];
  const float* b1   = (const float*)d_in[6];
  const float* W2   = (const float*)d_in[7];
  const float* b2   = (const float*)d_in[8];
  const float* ln1g = (const float*)d_in[9];
  const float* ln1b = (const float*)d_in[10];
  const float* ln2g = (const float*)d_in[11];
  const float* ln2b = (const float*)d_in[12];
  const float* lnfg = (const float*)d_in[13];
  const float* lnfb = (const float*)d_in[14];
  float* out = (float*)d_out;

  const int M = BB * TT;                 // 8192
  const int ND = M * DD;

  float* x = (float*)d_ws;
  __hip_bfloat16* sb  = (__hip_bfloat16*)(x + ND);
  __hip_bfloat16* big = sb + (size_t)M * DD;
  __hip_bfloat16* wqb = big + (size_t)M * FF;
  __hip_bfloat16* wob = wqb + (size_t)NL * 3 * DD * DD;
  __hip_bfloat16* w1b = wob + (size_t)NL * DD * DD;
  __hip_bfloat16* w2b = w1b + (size_t)NL * FF * DD;

  prologue_kernel<<<3072 + M / 4, 256, 0, stream>>>(
      (const float4*)Wqkv, (const float4*)Wo, (const float4*)W1,
      (const float4*)W2, (ushort4*)wqb, tokens, ln1g, ln1b, x, sb);

  for (int l = 0; l < NL; ++l) {
    // qkv: 64x64 tiles, BK=64 -> grid (12,128)=1536 blocks (~6/CU resident)
    mgemm_kernel<2, 2, 64, 256, 0><<<dim3(12, 128), 256, 0, stream>>>(
        sb, wqb + (size_t)l * 768 * DD, bqkv + l * 768, big, M, 768);
    attn_kernel<<<dim3(TT / 64, BB * 4), 256, 0, stream>>>(big, sb);
    // Wo + residual + ln2 (K=256 -> 4 iters of BK=64)
    mgemm_ln_kernel<256, 0><<<M / 32, 256, 0, stream>>>(
        sb, wob + (size_t)l * DD * DD, bo + l * DD, x,
        ln2g + l * DD, ln2b + l * DD, x, sb);
    // W1 + GELU: 64x64 tiles, BK=64 -> grid (16,128)=2048 blocks (~8/CU)
    mgemm_kernel<2, 2, 64, 256, 1><<<dim3(16, 128), 256, 0, stream>>>(
        sb, w1b + (size_t)l * FF * DD, b1 + l * FF, big, M, FF);
    // W2 + residual + (next ln1 | final LN -> d_out), K=1024 -> 16 iters BK=64
    if (l < NL - 1) {
      mgemm_ln_kernel<1024, 0><<<M / 32, 256, 0, stream>>>(
          big, w2b + (size_t)l * DD * FF, b2 + l * DD, x,
          ln1g + (l + 1) * DD, ln1b + (l + 1) * DD, x, sb);
    } else {
      mgemm_ln_kernel<1024, 1><<<M / 32, 256, 0, stream>>>(
          big, w2b + (size_t)l * DD * FF, b2 + l * DD, x,
          lnfg, lnfb, nullptr, out);
    }
  }
}

// Round 9
// 371.710 us; speedup vs baseline: 1.0171x; 1.0171x over previous
//
#include <hip/hip_runtime.h>
#include <hip/hip_bf16.h>
#include <math.h>

#define BB 4
#define TT 2048
#define DD 256
#define FF 1024
#define NL 4

typedef __bf16 bf16x8 __attribute__((ext_vector_type(8)));
typedef float f32x4 __attribute__((ext_vector_type(4)));

// fast exact-GELU: 0.5x(1+erf(x/sqrt2)), erf via A&S 7.1.26 (|err|<1.5e-7)
__device__ __forceinline__ float gelu_f(float v) {
  float x = fabsf(v) * 0.70710678118654752f;
  float t = 1.0f / fmaf(0.3275911f, x, 1.0f);
  float p = t * fmaf(t, fmaf(t, fmaf(t, fmaf(t, 1.061405429f, -1.453152027f),
                                     1.421413741f), -0.284496736f), 0.254829592f);
  float erfv = copysignf(1.0f - p * __expf(-x * x), v);
  return 0.5f * v * (1.0f + erfv);
}

// ---------------- prologue: weight f32->bf16 (blocks 0..3071) + PE+LN0 (rest) ----
__global__ __launch_bounds__(256) void prologue_kernel(
    const float4* __restrict__ wq, const float4* __restrict__ wo,
    const float4* __restrict__ w1, const float4* __restrict__ w2,
    ushort4* __restrict__ dst,
    const float* __restrict__ tokens, const float* __restrict__ g,
    const float* __restrict__ b, float* __restrict__ x,
    __hip_bfloat16* __restrict__ sb) {
  if (blockIdx.x < 3072) {
    int gi = blockIdx.x * 256 + threadIdx.x;
    const float4* src;
    int off;
    if (gi < 196608)      { src = wq; off = gi; }
    else if (gi < 262144) { src = wo; off = gi - 196608; }
    else if (gi < 524288) { src = w1; off = gi - 262144; }
    else                  { src = w2; off = gi - 524288; }
    float4 v = src[off];
    ushort4 o;
    o.x = __hip_bfloat16_raw(__float2bfloat16(v.x)).x;
    o.y = __hip_bfloat16_raw(__float2bfloat16(v.y)).x;
    o.z = __hip_bfloat16_raw(__float2bfloat16(v.z)).x;
    o.w = __hip_bfloat16_raw(__float2bfloat16(v.w)).x;
    dst[gi] = o;
    return;
  }
  int row = (blockIdx.x - 3072) * 4 + (threadIdx.x >> 6);
  int lane = threadIdx.x & 63;
  int t = row & (TT - 1);
  const float* xr = tokens + (size_t)row * DD;
  float v[4];
  float s = 0.f;
#pragma unroll
  for (int i = 0; i < 4; ++i) {
    int d = lane + 64 * i;
    int i2 = d & ~1;
    float freq = expf((float)i2 * -(9.210340371976184f / 256.f));
    float ang = (float)t * freq;
    float pe = (d & 1) ? cosf(ang) : sinf(ang);
    v[i] = xr[d] + pe;
    s += v[i];
  }
#pragma unroll
  for (int off = 32; off; off >>= 1) s += __shfl_xor(s, off, 64);
  float mu = s * (1.f / DD);
  float vs = 0.f;
#pragma unroll
  for (int i = 0; i < 4; ++i) { float dd = v[i] - mu; vs = fmaf(dd, dd, vs); }
#pragma unroll
  for (int off = 32; off; off >>= 1) vs += __shfl_xor(vs, off, 64);
  float rr = rsqrtf(vs * (1.f / DD) + 1e-5f);
#pragma unroll
  for (int i = 0; i < 4; ++i) {
    int d = lane + 64 * i;
    x[(size_t)row * DD + d] = v[i];
    sb[(size_t)row * DD + d] = __float2bfloat16((v[i] - mu) * rr * g[d] + b[d]);
  }
}

// ---------------- bf16 MFMA GEMM, chunked LDS ----------
// Block tile 32MW x 32NW, 4 waves 2x2 (wave tile 16MW x 16NW). LDS layout:
// [chunk c][row][32 bf16]. BK template; KTOT compile-time.
template <int MW, int NW, int BK, int KTOT, int ACT>
__global__ __launch_bounds__(256) void mgemm_kernel(
    const __hip_bfloat16* __restrict__ A, const __hip_bfloat16* __restrict__ B,
    const float* __restrict__ bias, __hip_bfloat16* __restrict__ Cout,
    int M, int N) {
  constexpr int BM = 32 * MW, BN = 32 * NW, ROWS = BM + BN;
  constexpr int NCH = BK / 32;
  constexpr int CHB = ROWS * 32;               // chunk stride in elems
  constexpr int RG = ROWS / 16;                // 16-row groups per chunk
  constexpr int NST = NCH * RG;                // stage instrs per kt-iter
  __shared__ __align__(16) __hip_bfloat16 sm[NCH * CHB];
  const int tid = threadIdx.x;
  const int wave = tid >> 6, lane = tid & 63;
  const int m0 = blockIdx.y * BM, n0 = blockIdx.x * BN;
  const int wm = (wave >> 1) * (16 * MW), wn = (wave & 1) * (16 * NW);
  const int quad = lane >> 4, lr = lane & 15;
  const int srow = lane >> 2, scol = (lane & 3) * 8;

  f32x4 acc[MW][NW] = {};

  for (int kt = 0; kt < KTOT; kt += BK) {
    __syncthreads();
#pragma unroll
    for (int i = 0; i < NST / 4; ++i) {
      int inst = i * 4 + wave;
      int c = inst / RG, grp = inst - c * RG;
      int r = grp * 16 + srow;
      const __hip_bfloat16* gp =
          (r < BM) ? (A + (size_t)(m0 + r) * KTOT + kt + c * 32 + scol)
                   : (B + (size_t)(n0 + (r - BM)) * KTOT + kt + c * 32 + scol);
      __builtin_amdgcn_global_load_lds(
          (const __attribute__((address_space(1))) unsigned int*)gp,
          (__attribute__((address_space(3))) unsigned int*)(sm + c * CHB + grp * 512),
          16, 0, 0);
    }
    __syncthreads();
#pragma unroll
    for (int c = 0; c < NCH; ++c) {
      bf16x8 af[MW], bfr[NW];
#pragma unroll
      for (int mi = 0; mi < MW; ++mi)
        af[mi] = *(const bf16x8*)(sm + c * CHB + (wm + mi * 16 + lr) * 32 + quad * 8);
#pragma unroll
      for (int ni = 0; ni < NW; ++ni)
        bfr[ni] = *(const bf16x8*)(sm + c * CHB + (BM + wn + ni * 16 + lr) * 32 + quad * 8);
#pragma unroll
      for (int mi = 0; mi < MW; ++mi)
#pragma unroll
        for (int ni = 0; ni < NW; ++ni)
          acc[mi][ni] = __builtin_amdgcn_mfma_f32_16x16x32_bf16(
              af[mi], bfr[ni], acc[mi][ni], 0, 0, 0);
    }
  }

#pragma unroll
  for (int mi = 0; mi < MW; ++mi) {
#pragma unroll
    for (int ni = 0; ni < NW; ++ni) {
      int col = n0 + wn + ni * 16 + lr;
      float bv = bias[col];
#pragma unroll
      for (int r = 0; r < 4; ++r) {
        int row = m0 + wm + mi * 16 + quad * 4 + r;
        float v = acc[mi][ni][r] + bv;
        if (ACT == 1) v = gelu_f(v);
        Cout[(size_t)row * N + col] = __float2bfloat16(v);
      }
    }
  }
}

// ---------------- bf16 GEMM, N=256 full-row, fused residual+LN (BK=64 chunks) ----
// BM=32, grid M/32=256. Wave w owns cols [64w,64w+64) x 32 rows.
template <int KTOT, int FIN>
__global__ __launch_bounds__(256) void mgemm_ln_kernel(
    const __hip_bfloat16* __restrict__ A, const __hip_bfloat16* __restrict__ B,
    const float* __restrict__ bias, const float* __restrict__ res,
    const float* __restrict__ g, const float* __restrict__ bb,
    float* __restrict__ xout, void* __restrict__ yout) {
  constexpr int BM = 32, ROWS = BM + 256;
  constexpr int BK = 64, NCH = BK / 32;
  constexpr int CHB = ROWS * 32;
  constexpr int RG = ROWS / 16;                // 18
  constexpr int NST = NCH * RG;                // 36
  __shared__ __align__(16) __hip_bfloat16 sm[NCH * CHB];
  __shared__ float red1[4][BM], red2[4][BM];
  const int tid = threadIdx.x;
  const int wave = tid >> 6, lane = tid & 63;
  const int quad = lane >> 4, lr = lane & 15;
  const int m0 = blockIdx.x * BM;
  const int srow = lane >> 2, scol = (lane & 3) * 8;

  f32x4 acc[2][4] = {};

  for (int kt = 0; kt < KTOT; kt += BK) {
    __syncthreads();
#pragma unroll
    for (int i = 0; i < NST / 4; ++i) {
      int inst = i * 4 + wave;
      int c = inst / RG, grp = inst - c * RG;
      int r = grp * 16 + srow;
      const __hip_bfloat16* gp =
          (r < BM) ? (A + (size_t)(m0 + r) * KTOT + kt + c * 32 + scol)
                   : (B + (size_t)(r - BM) * KTOT + kt + c * 32 + scol);
      __builtin_amdgcn_global_load_lds(
          (const __attribute__((address_space(1))) unsigned int*)gp,
          (__attribute__((address_space(3))) unsigned int*)(sm + c * CHB + grp * 512),
          16, 0, 0);
    }
    __syncthreads();
#pragma unroll
    for (int c = 0; c < NCH; ++c) {
      bf16x8 af[2], bfr[4];
#pragma unroll
      for (int mi = 0; mi < 2; ++mi)
        af[mi] = *(const bf16x8*)(sm + c * CHB + (mi * 16 + lr) * 32 + quad * 8);
#pragma unroll
      for (int ni = 0; ni < 4; ++ni)
        bfr[ni] = *(const bf16x8*)(sm + c * CHB + (BM + wave * 64 + ni * 16 + lr) * 32 + quad * 8);
#pragma unroll
      for (int mi = 0; mi < 2; ++mi)
#pragma unroll
        for (int ni = 0; ni < 4; ++ni)
          acc[mi][ni] = __builtin_amdgcn_mfma_f32_16x16x32_bf16(
              af[mi], bfr[ni], acc[mi][ni], 0, 0, 0);
    }
  }

  // epilogue: v = acc + bias + res; LN over full 256-col rows
  float v[2][4][4];
  float s1[2][4] = {}, s2[2][4] = {};
#pragma unroll
  for (int mi = 0; mi < 2; ++mi)
#pragma unroll
    for (int ni = 0; ni < 4; ++ni) {
      int col = wave * 64 + ni * 16 + lr;
      float bv = bias[col];
#pragma unroll
      for (int r = 0; r < 4; ++r) {
        int row = m0 + mi * 16 + quad * 4 + r;
        float val = acc[mi][ni][r] + bv + res[(size_t)row * DD + col];
        v[mi][ni][r] = val;
        s1[mi][r] += val;
        s2[mi][r] = fmaf(val, val, s2[mi][r]);
      }
    }
#pragma unroll
  for (int mi = 0; mi < 2; ++mi)
#pragma unroll
    for (int r = 0; r < 4; ++r) {
#pragma unroll
      for (int off = 8; off; off >>= 1) {
        s1[mi][r] += __shfl_xor(s1[mi][r], off, 64);
        s2[mi][r] += __shfl_xor(s2[mi][r], off, 64);
      }
    }
  if (lr == 0) {
#pragma unroll
    for (int mi = 0; mi < 2; ++mi)
#pragma unroll
      for (int r = 0; r < 4; ++r) {
        red1[wave][mi * 16 + quad * 4 + r] = s1[mi][r];
        red2[wave][mi * 16 + quad * 4 + r] = s2[mi][r];
      }
  }
  __syncthreads();
#pragma unroll
  for (int mi = 0; mi < 2; ++mi)
#pragma unroll
    for (int r = 0; r < 4; ++r) {
      int rl = mi * 16 + quad * 4 + r;
      float ssum = red1[0][rl] + red1[1][rl] + red1[2][rl] + red1[3][rl];
      float qsum = red2[0][rl] + red2[1][rl] + red2[2][rl] + red2[3][rl];
      float mu = ssum * (1.f / DD);
      float var = qsum * (1.f / DD) - mu * mu;
      float rr = rsqrtf(var + 1e-5f);
      int row = m0 + rl;
#pragma unroll
      for (int ni = 0; ni < 4; ++ni) {
        int col = wave * 64 + ni * 16 + lr;
        float y = (v[mi][ni][r] - mu) * rr * g[col] + bb[col];
        if (FIN) {
          ((float*)yout)[(size_t)row * DD + col] = y;
        } else {
          ((__hip_bfloat16*)yout)[(size_t)row * DD + col] = __float2bfloat16(y);
          xout[(size_t)row * DD + col] = v[mi][ni][r];
        }
      }
    }
}

// ---------------- sliding-window attention, MFMA ----------------
// LDS: KsPs (Ks 128x72 aliased with Ps 64x136 after QK^T) + Vt. 35 KB total
// -> 4 blocks/CU (was 53 KB -> 64 KB alloc -> 2 blocks/CU).
__global__ __launch_bounds__(256) void attn_kernel(const __hip_bfloat16* __restrict__ qkv,
                                                   __hip_bfloat16* __restrict__ o) {
  __shared__ __align__(16) __hip_bfloat16 KsPs[128 * 72]; // Ks[si][72] / Ps[w*16+row][136]
  __shared__ __align__(16) __hip_bfloat16 Vt[64 * 136];   // V^T, si-chunk XOR d>>3
  const int bh = blockIdx.y;
  const int b = bh >> 2, h = bh & 3;
  const int t0 = blockIdx.x * 64;
  const int sbase = t0 - 63;
  const int tid = threadIdx.x;

  const __hip_bfloat16* kb = qkv + (size_t)(b * TT) * 768 + 256 + h * 64;
  const __hip_bfloat16* vb = kb + 256;
  union U8 { uint4 u; __hip_bfloat16 hx[8]; };
#pragma unroll
  for (int it = 0; it < 4; ++it) {
    int f = tid + it * 256;
    int si = f >> 3;
    int c8 = f & 7;
    int s = sbase + si;
    U8 kr, vr;
    kr.u = make_uint4(0, 0, 0, 0); vr.u = make_uint4(0, 0, 0, 0);
    if (s >= 0 && s < TT) {
      kr.u = *(const uint4*)&kb[(size_t)s * 768 + 8 * c8];
      vr.u = *(const uint4*)&vb[(size_t)s * 768 + 8 * c8];
    }
    *(uint4*)&KsPs[si * 72 + c8 * 8] = kr.u;
    int pc = (si >> 3) ^ c8;
#pragma unroll
    for (int j = 0; j < 8; ++j) Vt[(c8 * 8 + j) * 136 + pc * 8 + (si & 7)] = vr.hx[j];
  }
  __syncthreads();

  const int wave = tid >> 6, lane = tid & 63;
  const int quad = lane >> 4, lr = lane & 15;

  // --- QK^T (reads Ks region of KsPs) ---
  const __hip_bfloat16* qrow = qkv + (size_t)(b * TT + t0 + wave * 16 + lr) * 768 + h * 64;
  bf16x8 qa0 = *(const bf16x8*)(qrow + quad * 8);
  bf16x8 qa1 = *(const bf16x8*)(qrow + 32 + quad * 8);
  f32x4 sc[8];
#pragma unroll
  for (int c = 0; c < 8; ++c) {
    f32x4 a = {};
    bf16x8 kf0 = *(const bf16x8*)&KsPs[(c * 16 + lr) * 72 + quad * 8];
    a = __builtin_amdgcn_mfma_f32_16x16x32_bf16(qa0, kf0, a, 0, 0, 0);
    bf16x8 kf1 = *(const bf16x8*)&KsPs[(c * 16 + lr) * 72 + 32 + quad * 8];
    a = __builtin_amdgcn_mfma_f32_16x16x32_bf16(qa1, kf1, a, 0, 0, 0);
    sc[c] = a;
  }
  __syncthreads();   // all Ks reads done; KsPs space now reused for Ps

  // --- masked softmax; write P into Ps region (per-wave rows, no sync) ---
#pragma unroll
  for (int reg = 0; reg < 4; ++reg) {
    int dt = wave * 16 + quad * 4 + reg;
    float pv[8];
    float mx = -1e30f;
#pragma unroll
    for (int c = 0; c < 8; ++c) {
      int si = c * 16 + lr;
      float v = sc[c][reg] * 0.125f;
      bool ok = (si >= dt) && (si <= dt + 63) && (sbase + si >= 0);
      v = ok ? v : -1e30f;
      pv[c] = v;
      mx = fmaxf(mx, v);
    }
#pragma unroll
    for (int off = 8; off; off >>= 1) mx = fmaxf(mx, __shfl_xor(mx, off, 64));
    float l = 0.f;
#pragma unroll
    for (int c = 0; c < 8; ++c) { float e = __expf(pv[c] - mx); pv[c] = e; l += e; }
#pragma unroll
    for (int off = 8; off; off >>= 1) l += __shfl_xor(l, off, 64);
    float rinv = 1.f / l;
#pragma unroll
    for (int c = 0; c < 8; ++c)
      KsPs[(wave * 16 + quad * 4 + reg) * 136 + c * 16 + lr] = __float2bfloat16(pv[c] * rinv);
  }

  // --- O = P V ---
  __hip_bfloat16* obase = o + (size_t)(b * TT) * DD + h * 64;
#pragma unroll
  for (int ct = 0; ct < 4; ++ct) {
    f32x4 acc = {};
#pragma unroll
    for (int kk = 0; kk < 4; ++kk) {
      bf16x8 pa = *(const bf16x8*)&KsPs[(wave * 16 + lr) * 136 + kk * 32 + quad * 8];
      int dd = ct * 16 + lr;
      bf16x8 vf = *(const bf16x8*)&Vt[dd * 136 + (((kk * 4 + quad) ^ (dd >> 3)) * 8)];
      acc = __builtin_amdgcn_mfma_f32_16x16x32_bf16(pa, vf, acc, 0, 0, 0);
    }
#pragma unroll
    for (int reg = 0; reg < 4; ++reg) {
      int t = t0 + wave * 16 + quad * 4 + reg;
      obase[(size_t)t * DD + ct * 16 + lr] = __float2bfloat16(acc[reg]);
    }
  }
}

extern "C" void kernel_launch(void* const* d_in, const int* in_sizes, int n_in,
                              void* d_out, int out_size, void* d_ws, size_t ws_size,
                              hipStream_t stream) {
  const float* tokens = (const float*)d_in[0];
  const float* Wqkv = (const float*)d_in[1];
  const float* bqkv = (const float*)d_in[2];
  const float* Wo   = (const float*)d_in[3];
  const float* bo   = (const float*)d_in[4];
  const float* W1   = (const float*)d_in[5];
  const float* b1   = (const float*)d_in[6];
  const float* W2   = (const float*)d_in[7];
  const float* b2   = (const float*)d_in[8];
  const float* ln1g = (const float*)d_in[9];
  const float* ln1b = (const float*)d_in[10];
  const float* ln2g = (const float*)d_in[11];
  const float* ln2b = (const float*)d_in[12];
  const float* lnfg = (const float*)d_in[13];
  const float* lnfb = (const float*)d_in[14];
  float* out = (float*)d_out;

  const int M = BB * TT;                 // 8192
  const int ND = M * DD;

  float* x = (float*)d_ws;
  __hip_bfloat16* sb  = (__hip_bfloat16*)(x + ND);
  __hip_bfloat16* big = sb + (size_t)M * DD;
  __hip_bfloat16* wqb = big + (size_t)M * FF;
  __hip_bfloat16* wob = wqb + (size_t)NL * 3 * DD * DD;
  __hip_bfloat16* w1b = wob + (size_t)NL * DD * DD;
  __hip_bfloat16* w2b = w1b + (size_t)NL * FF * DD;

  prologue_kernel<<<3072 + M / 4, 256, 0, stream>>>(
      (const float4*)Wqkv, (const float4*)Wo, (const float4*)W1,
      (const float4*)W2, (ushort4*)wqb, tokens, ln1g, ln1b, x, sb);

  for (int l = 0; l < NL; ++l) {
    // qkv: 64x128 tiles, BK=64 -> grid (6,128)=768 blocks (~3/CU)
    mgemm_kernel<2, 4, 64, 256, 0><<<dim3(6, 128), 256, 0, stream>>>(
        sb, wqb + (size_t)l * 768 * DD, bqkv + l * 768, big, M, 768);
    attn_kernel<<<dim3(TT / 64, BB * 4), 256, 0, stream>>>(big, sb);
    // Wo + residual + ln2 (K=256 -> 4 iters of BK=64)
    mgemm_ln_kernel<256, 0><<<M / 32, 256, 0, stream>>>(
        sb, wob + (size_t)l * DD * DD, bo + l * DD, x,
        ln2g + l * DD, ln2b + l * DD, x, sb);
    // W1 + GELU: 64x128 tiles, BK=64 -> grid (8,128)=1024 blocks (~4/CU)
    mgemm_kernel<2, 4, 64, 256, 1><<<dim3(8, 128), 256, 0, stream>>>(
        sb, w1b + (size_t)l * FF * DD, b1 + l * FF, big, M, FF);
    // W2 + residual + (next ln1 | final LN -> d_out), K=1024 -> 16 iters BK=64
    if (l < NL - 1) {
      mgemm_ln_kernel<1024, 0><<<M / 32, 256, 0, stream>>>(
          big, w2b + (size_t)l * DD * FF, b2 + l * DD, x,
          ln1g + (l + 1) * DD, ln1b + (l + 1) * DD, x, sb);
    } else {
      mgemm_ln_kernel<1024, 1><<<M / 32, 256, 0, stream>>>(
          big, w2b + (size_t)l * DD * FF, b2 + l * DD, x,
          lnfg, lnfb, nullptr, out);
    }
  }
}